// Round 1
// baseline (314.337 us; speedup 1.0000x reference)
//
#include <hip/hip_runtime.h>
#include <hip/hip_bf16.h>
#include <stdint.h>

// MultiHeadAttention: B=2, L=2048, D=1024, H=16, F=64
// Pipeline: cvt(fp32->bf16) -> GEMM qkv (bf16 MFMA, scatter to [b,h,l,f])
//           -> flash attention (bf16 MFMA, online softmax)
//           -> GEMM proj (bf16 MFMA, fp32 out)

typedef unsigned short u16;
typedef __attribute__((ext_vector_type(8))) short short8;
typedef __attribute__((ext_vector_type(4))) float f32x4;

#define MFMA16(a, b, c) __builtin_amdgcn_mfma_f32_16x16x32_bf16((a), (b), (c), 0, 0, 0)

__device__ __forceinline__ u16 f2bf(float x) {
  union { float f; uint32_t u; } v; v.f = x;
  uint32_t r = v.u + 0x7FFFu + ((v.u >> 16) & 1u);
  return (u16)(r >> 16);
}

__device__ __forceinline__ void gload16(const void* g, void* l) {
  __builtin_amdgcn_global_load_lds((const __attribute__((address_space(1))) void*)g,
                                   (__attribute__((address_space(3))) void*)l, 16, 0, 0);
}

// ---------------- fp32 -> bf16 convert ----------------
__global__ __launch_bounds__(256) void cvt_kernel(const float* __restrict__ src,
                                                  u16* __restrict__ dst, int n4) {
  int i = blockIdx.x * 256 + threadIdx.x;
  if (i >= n4) return;
  float4 f = reinterpret_cast<const float4*>(src)[i];
  ushort4 o;
  o.x = f2bf(f.x); o.y = f2bf(f.y); o.z = f2bf(f.z); o.w = f2bf(f.w);
  reinterpret_cast<ushort4*>(dst)[i] = o;
}

// ---------------- bf16 GEMM: C[M][N] = A[M][K] * B[N][K]^T + bias ----------------
// 128x128 tile, BK=32, 4 waves (2x2), each wave 64x64 = 4x4 frags of 16x16.
// EPI 0: scatter bf16 into qkv [3][2][16][2048][64]; EPI 1: fp32 row-major out.
template <int EPI>
__global__ __launch_bounds__(256) void gemm_bt(const u16* __restrict__ A,
                                               const u16* __restrict__ B,
                                               const float* __restrict__ bias,
                                               u16* __restrict__ outb,
                                               float* __restrict__ outf,
                                               int M, int N, int K) {
  __shared__ u16 sA[128 * 32];
  __shared__ u16 sB[128 * 32];
  const int tid = threadIdx.x;
  const int lane = tid & 63;
  const int wid = tid >> 6;
  const int bn = blockIdx.x, bm = blockIdx.y;
  const int row0 = bm * 128, col0 = bn * 128;
  const int wr = wid >> 1, wc = wid & 1;
  const int fr = lane & 15, fq = lane >> 4;

  f32x4 acc[4][4];
  #pragma unroll
  for (int m = 0; m < 4; m++)
    #pragma unroll
    for (int n = 0; n < 4; n++)
      #pragma unroll
      for (int j = 0; j < 4; j++) acc[m][n][j] = 0.f;

  const int e1 = tid * 8;         // element offset in 128x32 tile (first half)
  const int e2 = e1 + 2048;       // second half
  const int r1 = e1 >> 5, c1 = e1 & 31;
  const int r2 = e2 >> 5;
  const u16* Ap1 = A + (size_t)(row0 + r1) * K + c1;
  const u16* Ap2 = A + (size_t)(row0 + r2) * K + c1;
  const u16* Bp1 = B + (size_t)(col0 + r1) * K + c1;
  const u16* Bp2 = B + (size_t)(col0 + r2) * K + c1;

  for (int k0 = 0; k0 < K; k0 += 32) {
    __syncthreads();
    gload16(Ap1 + k0, &sA[e1]);
    gload16(Ap2 + k0, &sA[e2]);
    gload16(Bp1 + k0, &sB[e1]);
    gload16(Bp2 + k0, &sB[e2]);
    __syncthreads();
    short8 a[4], b[4];
    #pragma unroll
    for (int m = 0; m < 4; m++)
      a[m] = *(const short8*)&sA[(wr * 64 + m * 16 + fr) * 32 + fq * 8];
    #pragma unroll
    for (int n = 0; n < 4; n++)
      b[n] = *(const short8*)&sB[(wc * 64 + n * 16 + fr) * 32 + fq * 8];
    #pragma unroll
    for (int m = 0; m < 4; m++)
      #pragma unroll
      for (int n = 0; n < 4; n++)
        acc[m][n] = MFMA16(a[m], b[n], acc[m][n]);
  }

  #pragma unroll
  for (int m = 0; m < 4; m++) {
    #pragma unroll
    for (int n = 0; n < 4; n++) {
      #pragma unroll
      for (int j = 0; j < 4; j++) {
        int r = row0 + wr * 64 + m * 16 + fq * 4 + j;
        int c = col0 + wc * 64 + n * 16 + fr;
        float v = acc[m][n][j] + bias[c];
        if (EPI == 0) {
          // c in [0,3072): cc = q/k/v, d = within 1024; r = b*2048 + l
          int cc = c >> 10, d = c & 1023, h = d >> 6, f = d & 63;
          int bb = r >> 11, ll = r & 2047;
          outb[(size_t)cc * 4194304u + ((size_t)((bb * 16 + h) * 2048 + ll) << 6) + f] = f2bf(v);
        } else {
          outf[(size_t)r * N + c] = v;
        }
      }
    }
  }
}

// ---------------- flash attention ----------------
// q,k,v: [32][2048][64] bf16 (bh-major). y: [2][2048][1024] bf16 (b, l, h*64+f).
// Block: 256 thr / 4 waves; wave handles 16 q rows; block 64 q rows. KV tile 32.
__global__ __launch_bounds__(256) void attn_kernel(const u16* __restrict__ qg,
                                                   const u16* __restrict__ kg,
                                                   const u16* __restrict__ vg,
                                                   u16* __restrict__ y) {
  __shared__ u16 sK[32][72];   // padded: 144B row stride
  __shared__ u16 sVt[64][40];  // V transposed [f][kv], 80B row stride
  __shared__ u16 sP[4][16][40];
  const int bh = blockIdx.y, qt = blockIdx.x;
  const int tid = threadIdx.x, lane = tid & 63, wid = tid >> 6;
  const int fr = lane & 15, fq = lane >> 4;
  const size_t base = (size_t)bh * 2048 * 64;
  const u16* qp = qg + base;
  const u16* kp = kg + base;
  const u16* vp = vg + base;
  const int qrow = qt * 64 + wid * 16;

  short8 qf0 = *(const short8*)&qp[(qrow + fr) * 64 + fq * 8];
  short8 qf1 = *(const short8*)&qp[(qrow + fr) * 64 + 32 + fq * 8];

  f32x4 o[4];
  #pragma unroll
  for (int i = 0; i < 4; i++)
    #pragma unroll
    for (int j = 0; j < 4; j++) o[i][j] = 0.f;
  float mrow[4] = {-1e30f, -1e30f, -1e30f, -1e30f};
  float lrow[4] = {0.f, 0.f, 0.f, 0.f};

  const int sr = tid >> 3;        // 0..31 (kv row in tile)
  const int sc = (tid & 7) * 8;   // 0..56 (f col)

  for (int t = 0; t < 2048; t += 32) {
    __syncthreads();
    // stage K row-major, V transposed
    *(short8*)&sK[sr][sc] = *(const short8*)&kp[(size_t)(t + sr) * 64 + sc];
    short8 vv = *(const short8*)&vp[(size_t)(t + sr) * 64 + sc];
    #pragma unroll
    for (int i = 0; i < 8; i++) sVt[sc + i][sr] = (u16)vv[i];
    __syncthreads();

    // S = Q K^T (two 16x16 col tiles)
    f32x4 s0, s1;
    #pragma unroll
    for (int j = 0; j < 4; j++) { s0[j] = 0.f; s1[j] = 0.f; }
    {
      short8 kb0 = *(const short8*)&sK[fr][fq * 8];
      short8 kb1 = *(const short8*)&sK[fr][32 + fq * 8];
      s0 = MFMA16(qf0, kb0, s0);
      s0 = MFMA16(qf1, kb1, s0);
      short8 kb2 = *(const short8*)&sK[16 + fr][fq * 8];
      short8 kb3 = *(const short8*)&sK[16 + fr][32 + fq * 8];
      s1 = MFMA16(qf0, kb2, s1);
      s1 = MFMA16(qf1, kb3, s1);
    }

    // online softmax over this 32-col tile; lane owns rows fq*4+j, col fr/16+fr
    #pragma unroll
    for (int j = 0; j < 4; j++) {
      float a0 = s0[j] * 0.125f, a1 = s1[j] * 0.125f;
      float tmax = fmaxf(a0, a1);
      #pragma unroll
      for (int d = 1; d < 16; d <<= 1) tmax = fmaxf(tmax, __shfl_xor(tmax, d));
      float nm = fmaxf(mrow[j], tmax);
      float scale = __expf(mrow[j] - nm);
      float p0 = __expf(a0 - nm), p1 = __expf(a1 - nm);
      float ps = p0 + p1;
      #pragma unroll
      for (int d = 1; d < 16; d <<= 1) ps += __shfl_xor(ps, d);
      lrow[j] = lrow[j] * scale + ps;
      mrow[j] = nm;
      #pragma unroll
      for (int ct = 0; ct < 4; ct++) o[ct][j] *= scale;
      sP[wid][fq * 4 + j][fr] = f2bf(p0);
      sP[wid][fq * 4 + j][16 + fr] = f2bf(p1);
    }
    __syncthreads();

    // O += P V  (A-frag from sP, B-frag from sVt)
    short8 pa = *(const short8*)&sP[wid][fr][fq * 8];
    #pragma unroll
    for (int ct = 0; ct < 4; ct++) {
      short8 vb = *(const short8*)&sVt[ct * 16 + fr][fq * 8];
      o[ct] = MFMA16(pa, vb, o[ct]);
    }
  }

  const int b = bh >> 4, h = bh & 15;
  #pragma unroll
  for (int j = 0; j < 4; j++) {
    int r = qrow + fq * 4 + j;
    float inv = 1.0f / lrow[j];
    #pragma unroll
    for (int ct = 0; ct < 4; ct++) {
      y[((size_t)(b * 2048 + r)) * 1024 + h * 64 + ct * 16 + fr] = f2bf(o[ct][j] * inv);
    }
  }
}

// ---------------- launcher ----------------
extern "C" void kernel_launch(void* const* d_in, const int* in_sizes, int n_in,
                              void* d_out, int out_size, void* d_ws, size_t ws_size,
                              hipStream_t stream) {
  const float* x = (const float*)d_in[0];       // [2,2048,1024]
  const float* w_qkv = (const float*)d_in[1];   // [3072,1024]
  const float* b_qkv = (const float*)d_in[2];   // [3072]
  const float* w_proj = (const float*)d_in[3];  // [1024,1024]
  const float* b_proj = (const float*)d_in[4];  // [1024]
  float* out = (float*)d_out;                   // [2,2048,1024] fp32

  u16* ws = (u16*)d_ws;
  u16* xb = ws;                       // 4,194,304
  u16* wq = xb + 4194304;             // 3,145,728
  u16* wp = wq + 3145728;             // 1,048,576
  u16* qb = wp + 1048576;             // q/k/v: 3 * 4,194,304
  u16* kb = qb + 4194304;
  u16* vb = kb + 4194304;
  u16* yb = vb + 4194304;             // 4,194,304
  // total 25,165,824 u16 = 48 MiB of d_ws

  cvt_kernel<<<4096, 256, 0, stream>>>(x, xb, 1048576);
  cvt_kernel<<<3072, 256, 0, stream>>>(w_qkv, wq, 786432);
  cvt_kernel<<<1024, 256, 0, stream>>>(w_proj, wp, 262144);

  // qkv = x @ w_qkv^T + b_qkv, scattered to [3][2][16][2048][64] bf16
  gemm_bt<0><<<dim3(24, 32), 256, 0, stream>>>(xb, wq, b_qkv, qb, nullptr, 4096, 3072, 1024);

  // flash attention -> y [2][2048][1024] bf16
  attn_kernel<<<dim3(32, 32), 256, 0, stream>>>(qb, kb, vb, yb);

  // out = y @ w_proj^T + b_proj (fp32)
  gemm_bt<1><<<dim3(8, 32), 256, 0, stream>>>(yb, wp, b_proj, nullptr, out, 4096, 1024, 1024);
}

// Round 2
// 190.046 us; speedup vs baseline: 1.6540x; 1.6540x over previous
//
#include <hip/hip_runtime.h>
#include <hip/hip_bf16.h>
#include <stdint.h>

// MultiHeadAttention: B=2, L=2048, D=1024, H=16, F=64
// cvt(fp32->bf16) -> GEMM qkv (writes q*0.125 [bh][l][f], k [bh][l][f], V^T [bh][f][l])
// -> flash attention (KVB=64, dbuf LDS, XOR-swizzled tiles) -> GEMM proj (fp32 out)

typedef unsigned short u16;
typedef __attribute__((ext_vector_type(8))) short short8;
typedef __attribute__((ext_vector_type(4))) float f32x4;

#define MFMA16(a, b, c) __builtin_amdgcn_mfma_f32_16x16x32_bf16((a), (b), (c), 0, 0, 0)

__device__ __forceinline__ u16 f2bf(float x) {
  union { float f; uint32_t u; } v; v.f = x;
  uint32_t r = v.u + 0x7FFFu + ((v.u >> 16) & 1u);
  return (u16)(r >> 16);
}

__device__ __forceinline__ void gload16(const void* g, void* l) {
  __builtin_amdgcn_global_load_lds((const __attribute__((address_space(1))) void*)g,
                                   (__attribute__((address_space(3))) void*)l, 16, 0, 0);
}

// ---------------- fp32 -> bf16 convert ----------------
__global__ __launch_bounds__(256) void cvt_kernel(const float* __restrict__ src,
                                                  u16* __restrict__ dst, int n4) {
  int i = blockIdx.x * 256 + threadIdx.x;
  if (i >= n4) return;
  float4 f = reinterpret_cast<const float4*>(src)[i];
  ushort4 o;
  o.x = f2bf(f.x); o.y = f2bf(f.y); o.z = f2bf(f.z); o.w = f2bf(f.w);
  reinterpret_cast<ushort4*>(dst)[i] = o;
}

// ---------------- bf16 GEMM: C[M][N] = A[M][K] * B[N][K]^T + bias ----------------
// EPI 0: scatter q (scaled 1/8) [bh][l][64], k [bh][l][64], V^T [bh][64][l] bf16.
// EPI 1: fp32 row-major out.
template <int EPI>
__global__ __launch_bounds__(256) void gemm_bt(const u16* __restrict__ A,
                                               const u16* __restrict__ B,
                                               const float* __restrict__ bias,
                                               u16* __restrict__ outb,
                                               float* __restrict__ outf,
                                               int M, int N, int K) {
  __shared__ u16 sA[128 * 32];
  __shared__ u16 sB[128 * 32];
  const int tid = threadIdx.x;
  const int lane = tid & 63;
  const int wid = tid >> 6;
  const int bn = blockIdx.x, bm = blockIdx.y;
  const int row0 = bm * 128, col0 = bn * 128;
  const int wr = wid >> 1, wc = wid & 1;
  const int fr = lane & 15, fq = lane >> 4;

  f32x4 acc[4][4];
  #pragma unroll
  for (int m = 0; m < 4; m++)
    #pragma unroll
    for (int n = 0; n < 4; n++)
      #pragma unroll
      for (int j = 0; j < 4; j++) acc[m][n][j] = 0.f;

  const int e1 = tid * 8;
  const int e2 = e1 + 2048;
  const int r1 = e1 >> 5, c1 = e1 & 31;
  const int r2 = e2 >> 5;
  const u16* Ap1 = A + (size_t)(row0 + r1) * K + c1;
  const u16* Ap2 = A + (size_t)(row0 + r2) * K + c1;
  const u16* Bp1 = B + (size_t)(col0 + r1) * K + c1;
  const u16* Bp2 = B + (size_t)(col0 + r2) * K + c1;

  for (int k0 = 0; k0 < K; k0 += 32) {
    __syncthreads();
    gload16(Ap1 + k0, &sA[e1]);
    gload16(Ap2 + k0, &sA[e2]);
    gload16(Bp1 + k0, &sB[e1]);
    gload16(Bp2 + k0, &sB[e2]);
    __syncthreads();
    short8 a[4], b[4];
    #pragma unroll
    for (int m = 0; m < 4; m++)
      a[m] = *(const short8*)&sA[(wr * 64 + m * 16 + fr) * 32 + fq * 8];
    #pragma unroll
    for (int n = 0; n < 4; n++)
      b[n] = *(const short8*)&sB[(wc * 64 + n * 16 + fr) * 32 + fq * 8];
    #pragma unroll
    for (int m = 0; m < 4; m++)
      #pragma unroll
      for (int n = 0; n < 4; n++)
        acc[m][n] = MFMA16(a[m], b[n], acc[m][n]);
  }

  #pragma unroll
  for (int m = 0; m < 4; m++) {
    #pragma unroll
    for (int n = 0; n < 4; n++) {
      #pragma unroll
      for (int j = 0; j < 4; j++) {
        int r = row0 + wr * 64 + m * 16 + fq * 4 + j;
        int c = col0 + wc * 64 + n * 16 + fr;
        float v = acc[m][n][j] + bias[c];
        if (EPI == 0) {
          int cc = c >> 10, d = c & 1023, h = d >> 6, f = d & 63;
          int bb = r >> 11, ll = r & 2047;
          int bhh = bb * 16 + h;
          if (cc == 0) {
            outb[((size_t)bhh * 2048 + ll) * 64 + f] = f2bf(v * 0.125f);
          } else if (cc == 1) {
            outb[4194304u + ((size_t)bhh * 2048 + ll) * 64 + f] = f2bf(v);
          } else {
            outb[8388608u + ((size_t)bhh * 64 + f) * 2048 + ll] = f2bf(v);
          }
        } else {
          outf[(size_t)r * N + c] = v;
        }
      }
    }
  }
}

// ---------------- flash attention ----------------
// q [bh][2048][64] (pre-scaled 1/8), k [bh][2048][64], vt [bh][64][2048], all bf16.
// Block: 256 thr / 4 waves; wave = 32 q rows (M_rep=2); block = 128 q rows; KVB=64.
// K/Vt double-buffered in LDS with XOR swizzle (u16 col ^= (row&7)<<3), staged via
// global_load_lds with pre-swizzled SOURCE addresses (linear LDS dest).
__global__ __launch_bounds__(256, 3) void attn_kernel(const u16* __restrict__ qg,
                                                      const u16* __restrict__ kg,
                                                      const u16* __restrict__ vtg,
                                                      u16* __restrict__ y) {
  __shared__ u16 sK[2][4096];
  __shared__ u16 sVt[2][4096];
  __shared__ u16 sP[4 * 2048];
  const int bh = blockIdx.y, qt = blockIdx.x;
  const int tid = threadIdx.x, lane = tid & 63, wid = tid >> 6;
  const int fr = lane & 15, fq = lane >> 4;
  const size_t base = (size_t)bh * 131072;
  const u16* qp = qg + base;
  const u16* kp = kg + base;
  const u16* vp = vtg + base;
  const int qrow = qt * 128 + wid * 32;

  // staging: chunk c -> row c>>3, 16B col (c&7); source col pre-swizzled
  const int c2 = tid + 256;
  const int r1 = tid >> 3, r2 = c2 >> 3;
  const int sw1 = ((tid & 7) * 8) ^ ((r1 & 7) << 3);  // u16 units
  const int sw2 = ((c2 & 7) * 8) ^ ((r2 & 7) << 3);
  const int ko1 = r1 * 64 + sw1, ko2 = r2 * 64 + sw2;
  const int vo1 = r1 * 2048 + sw1, vo2 = r2 * 2048 + sw2;
  const int d1 = tid * 8, d2 = c2 * 8;

  short8 qf[2][2];
  #pragma unroll
  for (int mr = 0; mr < 2; mr++)
    #pragma unroll
    for (int hh = 0; hh < 2; hh++)
      qf[mr][hh] = *(const short8*)&qp[(size_t)(qrow + mr * 16 + fr) * 64 + hh * 32 + fq * 8];

  f32x4 o[2][4];
  float mrow[2][4], lrow[2][4];
  #pragma unroll
  for (int mr = 0; mr < 2; mr++)
    #pragma unroll
    for (int j = 0; j < 4; j++) {
      mrow[mr][j] = -1e30f; lrow[mr][j] = 0.f;
      #pragma unroll
      for (int ct = 0; ct < 4; ct++) o[mr][ct][j] = 0.f;
    }

  const int swr = (fr & 7) << 3;  // read-side swizzle (u16 units)

  // prologue: stage tile 0 into buffer 0
  gload16(kp + ko1, &sK[0][d1]);
  gload16(kp + ko2, &sK[0][d2]);
  gload16(vp + vo1, &sVt[0][d1]);
  gload16(vp + vo2, &sVt[0][d2]);

  int sel = 0;
  for (int t0 = 0; t0 < 2048; t0 += 64) {
    __syncthreads();  // buf[sel] ready; prior reads of buf[sel^1] complete
    if (t0 + 64 < 2048) {
      const int tn = t0 + 64;
      gload16(kp + (size_t)tn * 64 + ko1, &sK[sel ^ 1][d1]);
      gload16(kp + (size_t)tn * 64 + ko2, &sK[sel ^ 1][d2]);
      gload16(vp + tn + vo1, &sVt[sel ^ 1][d1]);
      gload16(vp + tn + vo2, &sVt[sel ^ 1][d2]);
    }
    const u16* Kt = sK[sel];
    const u16* Vt = sVt[sel];
    u16* P = &sP[wid * 2048];

    // S = Q K^T : s[mr][n], rows fq*4+j (within mr tile), col n*16+fr
    f32x4 s[2][4];
    #pragma unroll
    for (int mr = 0; mr < 2; mr++)
      #pragma unroll
      for (int n = 0; n < 4; n++)
        #pragma unroll
        for (int j = 0; j < 4; j++) s[mr][n][j] = 0.f;
    #pragma unroll
    for (int n = 0; n < 4; n++) {
      short8 kb0 = *(const short8*)&Kt[(n * 16 + fr) * 64 + ((fq * 8) ^ swr)];
      short8 kb1 = *(const short8*)&Kt[(n * 16 + fr) * 64 + ((32 + fq * 8) ^ swr)];
      s[0][n] = MFMA16(qf[0][0], kb0, s[0][n]);
      s[0][n] = MFMA16(qf[0][1], kb1, s[0][n]);
      s[1][n] = MFMA16(qf[1][0], kb0, s[1][n]);
      s[1][n] = MFMA16(qf[1][1], kb1, s[1][n]);
    }

    // online softmax (16-lane groups across kv), P -> LDS (swizzled)
    #pragma unroll
    for (int mr = 0; mr < 2; mr++) {
      #pragma unroll
      for (int j = 0; j < 4; j++) {
        float a0 = s[mr][0][j], a1 = s[mr][1][j], a2 = s[mr][2][j], a3 = s[mr][3][j];
        float tmax = fmaxf(fmaxf(a0, a1), fmaxf(a2, a3));
        #pragma unroll
        for (int d = 1; d < 16; d <<= 1) tmax = fmaxf(tmax, __shfl_xor(tmax, d));
        float nm = fmaxf(mrow[mr][j], tmax);
        float sc = __expf(mrow[mr][j] - nm);
        float p0 = __expf(a0 - nm), p1 = __expf(a1 - nm);
        float p2 = __expf(a2 - nm), p3 = __expf(a3 - nm);
        float ps = (p0 + p1) + (p2 + p3);
        #pragma unroll
        for (int d = 1; d < 16; d <<= 1) ps += __shfl_xor(ps, d);
        lrow[mr][j] = lrow[mr][j] * sc + ps;
        mrow[mr][j] = nm;
        #pragma unroll
        for (int ct = 0; ct < 4; ct++) o[mr][ct][j] *= sc;
        int row = mr * 16 + fq * 4 + j;
        int swz = ((fq * 4 + j) & 7) << 3;
        P[row * 64 + (fr ^ swz)] = f2bf(p0);
        P[row * 64 + ((16 + fr) ^ swz)] = f2bf(p1);
        P[row * 64 + ((32 + fr) ^ swz)] = f2bf(p2);
        P[row * 64 + ((48 + fr) ^ swz)] = f2bf(p3);
      }
    }

    // O += P V  (P wave-private: no barrier needed)
    short8 pa[2][2];
    #pragma unroll
    for (int mr = 0; mr < 2; mr++) {
      pa[mr][0] = *(const short8*)&P[(mr * 16 + fr) * 64 + ((fq * 8) ^ swr)];
      pa[mr][1] = *(const short8*)&P[(mr * 16 + fr) * 64 + ((32 + fq * 8) ^ swr)];
    }
    #pragma unroll
    for (int ct = 0; ct < 4; ct++) {
      short8 vb0 = *(const short8*)&Vt[(ct * 16 + fr) * 64 + ((fq * 8) ^ swr)];
      short8 vb1 = *(const short8*)&Vt[(ct * 16 + fr) * 64 + ((32 + fq * 8) ^ swr)];
      #pragma unroll
      for (int mr = 0; mr < 2; mr++) {
        o[mr][ct] = MFMA16(pa[mr][0], vb0, o[mr][ct]);
        o[mr][ct] = MFMA16(pa[mr][1], vb1, o[mr][ct]);
      }
    }
    sel ^= 1;
  }

  const int b = bh >> 4, h = bh & 15;
  #pragma unroll
  for (int mr = 0; mr < 2; mr++) {
    #pragma unroll
    for (int j = 0; j < 4; j++) {
      int r = qrow + mr * 16 + fq * 4 + j;
      float inv = 1.0f / lrow[mr][j];
      #pragma unroll
      for (int ct = 0; ct < 4; ct++) {
        y[((size_t)(b * 2048 + r)) * 1024 + h * 64 + ct * 16 + fr] = f2bf(o[mr][ct][j] * inv);
      }
    }
  }
}

// ---------------- launcher ----------------
extern "C" void kernel_launch(void* const* d_in, const int* in_sizes, int n_in,
                              void* d_out, int out_size, void* d_ws, size_t ws_size,
                              hipStream_t stream) {
  const float* x = (const float*)d_in[0];
  const float* w_qkv = (const float*)d_in[1];
  const float* b_qkv = (const float*)d_in[2];
  const float* w_proj = (const float*)d_in[3];
  const float* b_proj = (const float*)d_in[4];
  float* out = (float*)d_out;

  u16* ws = (u16*)d_ws;
  u16* xb = ws;                       // 4,194,304
  u16* wq = xb + 4194304;             // 3,145,728
  u16* wp = wq + 3145728;             // 1,048,576
  u16* qb = wp + 1048576;             // q / k / vt: 3 * 4,194,304
  u16* kb = qb + 4194304;
  u16* vb = kb + 4194304;
  u16* yb = vb + 4194304;             // 4,194,304

  cvt_kernel<<<4096, 256, 0, stream>>>(x, xb, 1048576);
  cvt_kernel<<<3072, 256, 0, stream>>>(w_qkv, wq, 786432);
  cvt_kernel<<<1024, 256, 0, stream>>>(w_proj, wp, 262144);

  gemm_bt<0><<<dim3(24, 32), 256, 0, stream>>>(xb, wq, b_qkv, qb, nullptr, 4096, 3072, 1024);

  attn_kernel<<<dim3(16, 32), 256, 0, stream>>>(qb, kb, vb, yb);

  gemm_bt<1><<<dim3(8, 32), 256, 0, stream>>>(yb, wp, b_proj, nullptr, out, 4096, 1024, 1024);
}

// Round 3
// 134.687 us; speedup vs baseline: 2.3338x; 1.4110x over previous
//
#include <hip/hip_runtime.h>
#include <hip/hip_bf16.h>
#include <stdint.h>

// MultiHeadAttention: B=2, L=2048, D=1024, H=16, F=64
// cvt(fp32->bf16) -> GEMM qkv (writes q*0.125*log2e [bh][l][f], k [bh][l][f], V^T [bh][f][l])
// -> flash attention (fixed-m exp2 softmax, swapped QK^T, KVB=64, dbuf LDS, XOR swizzle)
// -> GEMM proj (fp32 out)

typedef unsigned short u16;
typedef __attribute__((ext_vector_type(8))) short short8;
typedef __attribute__((ext_vector_type(4))) float f32x4;

#define MFMA16(a, b, c) __builtin_amdgcn_mfma_f32_16x16x32_bf16((a), (b), (c), 0, 0, 0)

__device__ __forceinline__ u16 f2bf(float x) {
  union { float f; uint32_t u; } v; v.f = x;
  uint32_t r = v.u + 0x7FFFu + ((v.u >> 16) & 1u);
  return (u16)(r >> 16);
}

__device__ __forceinline__ float fexp2(float x) {
#if __has_builtin(__builtin_amdgcn_exp2f)
  return __builtin_amdgcn_exp2f(x);
#else
  return exp2f(x);
#endif
}

// pack two f32 -> two bf16 (round half-up) in one u32: u16[0]=bf(lo), u16[1]=bf(hi)
__device__ __forceinline__ uint32_t pkbf(float lo, float hi) {
  uint32_t a = __builtin_bit_cast(uint32_t, lo) + 0x8000u;
  uint32_t b = __builtin_bit_cast(uint32_t, hi) + 0x8000u;
  return __builtin_amdgcn_perm(b, a, 0x07060302u);
}

__device__ __forceinline__ void gload16(const void* g, void* l) {
  __builtin_amdgcn_global_load_lds((const __attribute__((address_space(1))) void*)g,
                                   (__attribute__((address_space(3))) void*)l, 16, 0, 0);
}

// ---------------- fp32 -> bf16 convert (merged: x, w_qkv, w_proj) ----------------
__global__ __launch_bounds__(256) void cvt_all(const float* __restrict__ x,
                                               const float* __restrict__ wq,
                                               const float* __restrict__ wp,
                                               u16* __restrict__ xb,
                                               u16* __restrict__ wqb,
                                               u16* __restrict__ wpb) {
  int i = blockIdx.x * 256 + threadIdx.x;  // total 2,097,152 float4 slots
  const float* s; u16* d; int off;
  if (i < 1048576) { s = x; d = xb; off = i; }
  else if (i < 1835008) { s = wq; d = wqb; off = i - 1048576; }
  else { s = wp; d = wpb; off = i - 1835008; }
  float4 f = reinterpret_cast<const float4*>(s)[off];
  ushort4 o;
  o.x = f2bf(f.x); o.y = f2bf(f.y); o.z = f2bf(f.z); o.w = f2bf(f.w);
  reinterpret_cast<ushort4*>(d)[off] = o;
}

// ---------------- bf16 GEMM: C[M][N] = A[M][K] * B[N][K]^T + bias ----------------
// EPI 0: scatter q (scaled 0.125*log2e) [bh][l][64], k [bh][l][64], V^T [bh][64][l].
// EPI 1: fp32 row-major out.
template <int EPI>
__global__ __launch_bounds__(256) void gemm_bt(const u16* __restrict__ A,
                                               const u16* __restrict__ B,
                                               const float* __restrict__ bias,
                                               u16* __restrict__ outb,
                                               float* __restrict__ outf,
                                               int M, int N, int K) {
  __shared__ u16 sA[128 * 32];
  __shared__ u16 sB[128 * 32];
  const int tid = threadIdx.x;
  const int lane = tid & 63;
  const int wid = tid >> 6;
  const int bn = blockIdx.x, bm = blockIdx.y;
  const int row0 = bm * 128, col0 = bn * 128;
  const int wr = wid >> 1, wc = wid & 1;
  const int fr = lane & 15, fq = lane >> 4;

  f32x4 acc[4][4];
  #pragma unroll
  for (int m = 0; m < 4; m++)
    #pragma unroll
    for (int n = 0; n < 4; n++)
      #pragma unroll
      for (int j = 0; j < 4; j++) acc[m][n][j] = 0.f;

  const int e1 = tid * 8;
  const int e2 = e1 + 2048;
  const int r1 = e1 >> 5, c1 = e1 & 31;
  const int r2 = e2 >> 5;
  const u16* Ap1 = A + (size_t)(row0 + r1) * K + c1;
  const u16* Ap2 = A + (size_t)(row0 + r2) * K + c1;
  const u16* Bp1 = B + (size_t)(col0 + r1) * K + c1;
  const u16* Bp2 = B + (size_t)(col0 + r2) * K + c1;

  for (int k0 = 0; k0 < K; k0 += 32) {
    __syncthreads();
    gload16(Ap1 + k0, &sA[e1]);
    gload16(Ap2 + k0, &sA[e2]);
    gload16(Bp1 + k0, &sB[e1]);
    gload16(Bp2 + k0, &sB[e2]);
    __syncthreads();
    short8 a[4], b[4];
    #pragma unroll
    for (int m = 0; m < 4; m++)
      a[m] = *(const short8*)&sA[(wr * 64 + m * 16 + fr) * 32 + fq * 8];
    #pragma unroll
    for (int n = 0; n < 4; n++)
      b[n] = *(const short8*)&sB[(wc * 64 + n * 16 + fr) * 32 + fq * 8];
    #pragma unroll
    for (int m = 0; m < 4; m++)
      #pragma unroll
      for (int n = 0; n < 4; n++)
        acc[m][n] = MFMA16(a[m], b[n], acc[m][n]);
  }

  #pragma unroll
  for (int m = 0; m < 4; m++) {
    #pragma unroll
    for (int n = 0; n < 4; n++) {
      #pragma unroll
      for (int j = 0; j < 4; j++) {
        int r = row0 + wr * 64 + m * 16 + fq * 4 + j;
        int c = col0 + wc * 64 + n * 16 + fr;
        float v = acc[m][n][j] + bias[c];
        if (EPI == 0) {
          int cc = c >> 10, d = c & 1023, h = d >> 6, f = d & 63;
          int bb = r >> 11, ll = r & 2047;
          int bhh = bb * 16 + h;
          if (cc == 0) {
            // 0.125 * log2(e): exp2(S') = exp(q.k/8)
            outb[((size_t)bhh * 2048 + ll) * 64 + f] = f2bf(v * 0.18033688f);
          } else if (cc == 1) {
            outb[4194304u + ((size_t)bhh * 2048 + ll) * 64 + f] = f2bf(v);
          } else {
            outb[8388608u + ((size_t)bhh * 64 + f) * 2048 + ll] = f2bf(v);
          }
        } else {
          outf[(size_t)r * N + c] = v;
        }
      }
    }
  }
}

// ---------------- flash attention (fixed-m softmax) ----------------
// q [bh][2048][64] (pre-scaled), k [bh][2048][64], vt [bh][64][2048], all bf16.
// 256 thr / 4 waves; wave = 32 q rows; block = 128 q rows; KVB = 64.
// Swapped QK^T: st = mfma(K, Q) -> lane owns P-row q=fr, kv = n*16+fq*4+j.
// Fixed m=0: P = exp2(S'), l accumulated per-lane, reduced once at epilogue.
__global__ __launch_bounds__(256, 2) void attn_kernel(const u16* __restrict__ qg,
                                                      const u16* __restrict__ kg,
                                                      const u16* __restrict__ vtg,
                                                      u16* __restrict__ y) {
  __shared__ u16 sK[2][4096];
  __shared__ u16 sVt[2][4096];
  __shared__ u16 sP[4][2048];
  const int x = blockIdx.x;
  const int bh = (x & 7) * 4 + (x >> 7);   // 4 bh per XCD: K+V = 2 MB, L2-resident
  const int qt = (x >> 3) & 15;
  const int tid = threadIdx.x, lane = tid & 63, wid = tid >> 6;
  const int fr = lane & 15, fq = lane >> 4;
  const size_t base = (size_t)bh * 131072;
  const u16* qp = qg + base;
  const u16* kp = kg + base;
  const u16* vp = vtg + base;
  const int qrow = qt * 128 + wid * 32;

  // staging: chunk c -> LDS row c>>3, 16B slot c&7; global source col pre-swizzled
  const int c2 = tid + 256;
  const int r1 = tid >> 3, r2 = c2 >> 3;
  const int sw1 = ((tid & 7) * 8) ^ ((r1 & 7) << 3);
  const int sw2 = ((c2 & 7) * 8) ^ ((r2 & 7) << 3);
  const int ko1 = r1 * 64 + sw1, ko2 = r2 * 64 + sw2;
  const int vo1 = r1 * 2048 + sw1, vo2 = r2 * 2048 + sw2;
  const int d1 = tid * 8, d2 = c2 * 8;

  short8 qf[2][2];
  #pragma unroll
  for (int mr = 0; mr < 2; mr++)
    #pragma unroll
    for (int hh = 0; hh < 2; hh++)
      qf[mr][hh] = *(const short8*)&qp[(size_t)(qrow + mr * 16 + fr) * 64 + hh * 32 + fq * 8];

  f32x4 o[2][4];
  float lp[2] = {0.f, 0.f};
  #pragma unroll
  for (int mr = 0; mr < 2; mr++)
    #pragma unroll
    for (int ct = 0; ct < 4; ct++)
      #pragma unroll
      for (int j = 0; j < 4; j++) o[mr][ct][j] = 0.f;

  const int swr = (fr & 7) << 3;  // read-side swizzle (u16 units)

  gload16(kp + ko1, &sK[0][d1]);
  gload16(kp + ko2, &sK[0][d2]);
  gload16(vp + vo1, &sVt[0][d1]);
  gload16(vp + vo2, &sVt[0][d2]);

  int sel = 0;
  for (int t0 = 0; t0 < 2048; t0 += 64) {
    __syncthreads();
    if (t0 + 64 < 2048) {
      const int tn = t0 + 64;
      gload16(kp + (size_t)tn * 64 + ko1, &sK[sel ^ 1][d1]);
      gload16(kp + (size_t)tn * 64 + ko2, &sK[sel ^ 1][d2]);
      gload16(vp + tn + vo1, &sVt[sel ^ 1][d1]);
      gload16(vp + tn + vo2, &sVt[sel ^ 1][d2]);
    }
    const u16* Kt = sK[sel];
    const u16* Vt = sVt[sel];
    u16* P = sP[wid];  // [32][64], wave-private

    // S^T = K Q^T : lane holds S[q=fr][kv = n*16 + fq*4 + j] in st[mr][n][j]
    f32x4 st[2][4];
    #pragma unroll
    for (int mr = 0; mr < 2; mr++)
      #pragma unroll
      for (int n = 0; n < 4; n++)
        #pragma unroll
        for (int j = 0; j < 4; j++) st[mr][n][j] = 0.f;
    #pragma unroll
    for (int n = 0; n < 4; n++) {
      short8 kb0 = *(const short8*)&Kt[(n * 16 + fr) * 64 + ((fq * 8) ^ swr)];
      short8 kb1 = *(const short8*)&Kt[(n * 16 + fr) * 64 + ((32 + fq * 8) ^ swr)];
      st[0][n] = MFMA16(kb0, qf[0][0], st[0][n]);
      st[0][n] = MFMA16(kb1, qf[0][1], st[0][n]);
      st[1][n] = MFMA16(kb0, qf[1][0], st[1][n]);
      st[1][n] = MFMA16(kb1, qf[1][1], st[1][n]);
    }

    // P = exp2(S'); per-lane l partial; pack pairs; b64 write (conflict-free)
    #pragma unroll
    for (int mr = 0; mr < 2; mr++) {
      const int prow = (mr * 16 + fr) * 64;
      #pragma unroll
      for (int n = 0; n < 4; n++) {
        float p0 = fexp2(st[mr][n][0]);
        float p1 = fexp2(st[mr][n][1]);
        float p2 = fexp2(st[mr][n][2]);
        float p3 = fexp2(st[mr][n][3]);
        lp[mr] += (p0 + p1) + (p2 + p3);
        uint2 w;
        w.x = pkbf(p0, p1);
        w.y = pkbf(p2, p3);
        *(uint2*)&P[prow + ((n * 16 + fq * 4) ^ swr)] = w;
      }
    }

    // O += P V (P wave-private: no barrier; compiler inserts lgkmcnt wait)
    short8 pa[2][2];
    #pragma unroll
    for (int mr = 0; mr < 2; mr++) {
      pa[mr][0] = *(const short8*)&P[(mr * 16 + fr) * 64 + ((fq * 8) ^ swr)];
      pa[mr][1] = *(const short8*)&P[(mr * 16 + fr) * 64 + ((32 + fq * 8) ^ swr)];
    }
    #pragma unroll
    for (int ct = 0; ct < 4; ct++) {
      short8 vb0 = *(const short8*)&Vt[(ct * 16 + fr) * 64 + ((fq * 8) ^ swr)];
      short8 vb1 = *(const short8*)&Vt[(ct * 16 + fr) * 64 + ((32 + fq * 8) ^ swr)];
      #pragma unroll
      for (int mr = 0; mr < 2; mr++) {
        o[mr][ct] = MFMA16(pa[mr][0], vb0, o[mr][ct]);
        o[mr][ct] = MFMA16(pa[mr][1], vb1, o[mr][ct]);
      }
    }
    sel ^= 1;
  }

  // epilogue: reduce l across fq groups, broadcast, normalize, store
  #pragma unroll
  for (int mr = 0; mr < 2; mr++) {
    lp[mr] += __shfl_xor(lp[mr], 16);
    lp[mr] += __shfl_xor(lp[mr], 32);
  }
  const int b = bh >> 4, h = bh & 15;
  #pragma unroll
  for (int mr = 0; mr < 2; mr++) {
    #pragma unroll
    for (int j = 0; j < 4; j++) {
      int r = qrow + mr * 16 + fq * 4 + j;
      float lq = __shfl(lp[mr], fq * 4 + j);
      float inv = 1.0f / lq;
      #pragma unroll
      for (int ct = 0; ct < 4; ct++) {
        y[((size_t)(b * 2048 + r)) * 1024 + h * 64 + ct * 16 + fr] = f2bf(o[mr][ct][j] * inv);
      }
    }
  }
}

// ---------------- launcher ----------------
extern "C" void kernel_launch(void* const* d_in, const int* in_sizes, int n_in,
                              void* d_out, int out_size, void* d_ws, size_t ws_size,
                              hipStream_t stream) {
  const float* x = (const float*)d_in[0];
  const float* w_qkv = (const float*)d_in[1];
  const float* b_qkv = (const float*)d_in[2];
  const float* w_proj = (const float*)d_in[3];
  const float* b_proj = (const float*)d_in[4];
  float* out = (float*)d_out;

  u16* ws = (u16*)d_ws;
  u16* xb = ws;                       // 4,194,304
  u16* wq = xb + 4194304;             // 3,145,728
  u16* wp = wq + 3145728;             // 1,048,576
  u16* qb = wp + 1048576;             // q / k / vt: 3 * 4,194,304
  u16* kb = qb + 4194304;
  u16* vb = kb + 4194304;
  u16* yb = vb + 4194304;             // 4,194,304

  cvt_all<<<8192, 256, 0, stream>>>(x, w_qkv, w_proj, xb, wq, wp);

  gemm_bt<0><<<dim3(24, 32), 256, 0, stream>>>(xb, wq, b_qkv, qb, nullptr, 4096, 3072, 1024);

  attn_kernel<<<512, 256, 0, stream>>>(qb, kb, vb, yb);

  gemm_bt<1><<<dim3(8, 32), 256, 0, stream>>>(yb, wp, b_proj, nullptr, out, 4096, 1024, 1024);
}